// Round 1
// baseline (640.961 us; speedup 1.0000x reference)
//
#include <hip/hip_runtime.h>
#include <hip/hip_bf16.h>
#include <stdint.h>

#define EPSF 1e-5f

typedef __attribute__((ext_vector_type(8))) short bf16x8;
typedef __attribute__((ext_vector_type(4))) float f32x4;
typedef __attribute__((ext_vector_type(8))) unsigned short u16x8;

__device__ __forceinline__ void gld_lds16(const void* g, void* l) {
  __builtin_amdgcn_global_load_lds((const __attribute__((address_space(1))) void*)g,
                                   (__attribute__((address_space(3))) void*)l, 16, 0, 0);
}

// ---------------- prep: binarize weights [1024 x Ksrc] -> bf16 [1024 x 1024], zero-pad ----------------
__global__ void k_binW(const float* __restrict__ src, ushort* __restrict__ dst, int Ksrc) {
  int t = blockIdx.x * 256 + threadIdx.x;  // 1024*128 threads, 8 elems each
  int c8 = (t & 127) << 3;
  u16x8 o;
  if (c8 < Ksrc) {
    int n = t >> 7;
    const float* p = src + (size_t)n * Ksrc + c8;
#pragma unroll
    for (int e = 0; e < 8; ++e) o[e] = (p[e] >= 0.0f) ? 0x3F80 : 0xBF80;
  } else {
    o = (u16x8)0;
  }
  *(u16x8*)(dst + (size_t)t * 8) = o;
}

// ---------------- input binarize: x [65536 x 784] -> X [65536 x 1024] bf16 +-1, pad 0 ----------------
// sign(2x-1) == (x >= 0.5) exactly (2x exact, Sterbenz subtraction exact)
__global__ void k_binX(const float* __restrict__ x, ushort* __restrict__ X) {
  size_t t = (size_t)blockIdx.x * 256 + threadIdx.x;  // 65536*128 threads
  int c8 = ((int)t & 127) << 3;
  u16x8 o;
  if (c8 < 784) {
    size_t b = t >> 7;
    const float* p = x + b * 784 + c8;
#pragma unroll
    for (int e = 0; e < 8; ++e) o[e] = (p[e] >= 0.5f) ? 0x3F80 : 0xBF80;
  } else {
    o = (u16x8)0;
  }
  *(u16x8*)(X + t * 8) = o;
}

// ---------------- small prep: inv_std (match numpy f32 rounding!) + binarized WL [16][1024] ----------------
__global__ void k_prep(const float* __restrict__ bn_gamma, const float* __restrict__ bn_var,
                       const float* __restrict__ bnL_gamma, const float* __restrict__ bnL_var,
                       const float* __restrict__ WL,
                       float* __restrict__ invstd3, float* __restrict__ invstdL,
                       ushort* __restrict__ WLb) {
  int j = threadIdx.x;  // 1024
#pragma unroll
  for (int i = 0; i < 3; ++i) {
    int idx = i * 1024 + j;
    invstd3[idx] = __fdiv_rn(bn_gamma[idx], __fsqrt_rn(__fadd_rn(bn_var[idx], EPSF)));
  }
  if (j < 10) invstdL[j] = __fdiv_rn(bnL_gamma[j], __fsqrt_rn(__fadd_rn(bnL_var[j], EPSF)));
#pragma unroll
  for (int r = 0; r < 16; ++r) {
    ushort v = 0;
    if (r < 10) v = (WL[r * 1024 + j] >= 0.0f) ? 0x3F80 : 0xBF80;
    WLb[r * 1024 + j] = v;
  }
}

// ---------------- main fused GEMM: C_bin = binarize(BN(A @ Bt^T)) ----------------
// A [M][1024] bf16 +-1, Bt [1024][1024] bf16 +-1 (row n = weight row n), out bf16 +-1.
// m97 structure: 128x128 tile, BK=32, 4 waves (2x2), 16 MFMA/K-step, global_load_lds w16.
__global__ __launch_bounds__(256, 2)
void gemm_bin(const ushort* __restrict__ A, const ushort* __restrict__ Bt,
              ushort* __restrict__ Cb,
              const float* __restrict__ mean, const float* __restrict__ beta,
              const float* __restrict__ invstd) {
  constexpr int K = 1024;
  __shared__ ushort sA[128 * 32];
  __shared__ ushort sB[128 * 32];
  const int tid = threadIdx.x;
  const int lane = tid & 63;
  const int wave = tid >> 6;
  const int bn = blockIdx.x;  // 0..7
  const int bm = blockIdx.y;  // 0..511
  const int wm = wave >> 1, wn = wave & 1;

  // staging: thread tid loads 16B -> LDS linear byte tid*16 (wave-uniform base + lane*16)
  const int sr = tid >> 2;
  const int sc = (tid & 3) << 3;
  const ushort* gA = A + ((size_t)(bm * 128 + sr)) * K + sc;
  const ushort* gB = Bt + ((size_t)(bn * 128 + sr)) * K + sc;
  char* lA = (char*)sA + (tid & ~63) * 16;
  char* lB = (char*)sB + (tid & ~63) * 16;

  // fragment read offsets: lane l -> row (l&15), k-chunk (l>>4)*8  (16B contiguous)
  const int kb = (lane >> 4) * 16;
  const char* rA = (const char*)sA + (wm * 64 + (lane & 15)) * 64 + kb;
  const char* rB = (const char*)sB + (wn * 64 + (lane & 15)) * 64 + kb;

  f32x4 acc[4][4];
#pragma unroll
  for (int m = 0; m < 4; ++m)
#pragma unroll
    for (int n = 0; n < 4; ++n) acc[m][n] = (f32x4)0.0f;

  for (int k0 = 0; k0 < K; k0 += 32) {
    gld_lds16(gA, lA);
    gld_lds16(gA + (size_t)64 * K, lA + 4096);
    gld_lds16(gB, lB);
    gld_lds16(gB + (size_t)64 * K, lB + 4096);
    gA += 32;
    gB += 32;
    __syncthreads();  // compiler drains vmcnt before barrier -> LDS ready
    bf16x8 af[4], bf[4];
#pragma unroll
    for (int m = 0; m < 4; ++m) af[m] = *(const bf16x8*)(rA + m * 16 * 64);
#pragma unroll
    for (int n = 0; n < 4; ++n) bf[n] = *(const bf16x8*)(rB + n * 16 * 64);
#pragma unroll
    for (int m = 0; m < 4; ++m)
#pragma unroll
      for (int n = 0; n < 4; ++n)
        acc[m][n] = __builtin_amdgcn_mfma_f32_16x16x32_bf16(af[m], bf[n], acc[m][n], 0, 0, 0);
    __syncthreads();
  }

  // epilogue: BN (exact np-f32 rounding: separate sub/mul/add, no FMA) + binarize
  // C/D map: col = lane&15, row = (lane>>4)*4 + reg
  const int r0 = bm * 128 + wm * 64 + ((lane >> 4) << 2);
  const int c0 = bn * 128 + wn * 64 + (lane & 15);
#pragma unroll
  for (int n = 0; n < 4; ++n) {
    const int col = c0 + n * 16;
    const float mu = mean[col], bt = beta[col], is = invstd[col];
#pragma unroll
    for (int m = 0; m < 4; ++m) {
#pragma unroll
      for (int j = 0; j < 4; ++j) {
        const int row = r0 + m * 16 + j;
        float y = __fadd_rn(__fmul_rn(__fsub_rn(acc[m][n][j], mu), is), bt);
        Cb[(size_t)row * 1024 + col] = (y >= 0.0f) ? 0x3F80 : 0xBF80;
      }
    }
  }
}

// ---------------- final layer: out[65536][10] = BN(A @ WLb^T), fp32 out ----------------
// Narrow variant: 128x16 tile, 4 waves each own 32 rows, 2 MFMA/K-step. Memory-bound.
__global__ __launch_bounds__(256, 2)
void gemm_fin(const ushort* __restrict__ A, const ushort* __restrict__ BtL,
              float* __restrict__ out,
              const float* __restrict__ meanL, const float* __restrict__ betaL,
              const float* __restrict__ invstdL) {
  constexpr int K = 1024;
  __shared__ ushort sA[128 * 32];
  __shared__ ushort sB[16 * 32];
  const int tid = threadIdx.x;
  const int lane = tid & 63;
  const int wave = tid >> 6;
  const int bm = blockIdx.x;

  const int sr = tid >> 2;
  const int sc = (tid & 3) << 3;
  const ushort* gA = A + ((size_t)(bm * 128 + sr)) * K + sc;
  const ushort* gB = BtL + (size_t)(tid >> 2) * K + sc;  // only wave 0 uses
  char* lA = (char*)sA + (tid & ~63) * 16;
  char* lB = (char*)sB;  // wave 0 covers all 1KB

  const int kb = (lane >> 4) * 16;
  const char* rA = (const char*)sA + (wave * 32 + (lane & 15)) * 64 + kb;
  const char* rB = (const char*)sB + (lane & 15) * 64 + kb;

  f32x4 acc0 = (f32x4)0.0f, acc1 = (f32x4)0.0f;

  for (int k0 = 0; k0 < K; k0 += 32) {
    gld_lds16(gA, lA);
    gld_lds16(gA + (size_t)64 * K, lA + 4096);
    if (tid < 64) gld_lds16(gB, lB);
    gA += 32;
    gB += 32;
    __syncthreads();
    bf16x8 af0 = *(const bf16x8*)(rA);
    bf16x8 af1 = *(const bf16x8*)(rA + 16 * 64);
    bf16x8 b0 = *(const bf16x8*)(rB);
    acc0 = __builtin_amdgcn_mfma_f32_16x16x32_bf16(af0, b0, acc0, 0, 0, 0);
    acc1 = __builtin_amdgcn_mfma_f32_16x16x32_bf16(af1, b0, acc1, 0, 0, 0);
    __syncthreads();
  }

  const int col = lane & 15;
  if (col < 10) {
    const float mu = meanL[col], bt = betaL[col], is = invstdL[col];
    const int r0 = bm * 128 + wave * 32 + ((lane >> 4) << 2);
#pragma unroll
    for (int m = 0; m < 2; ++m) {
      const f32x4 a = (m == 0) ? acc0 : acc1;
#pragma unroll
      for (int j = 0; j < 4; ++j) {
        const int row = r0 + m * 16 + j;
        out[(size_t)row * 10 + col] = __fadd_rn(__fmul_rn(__fsub_rn(a[j], mu), is), bt);
      }
    }
  }
}

extern "C" void kernel_launch(void* const* d_in, const int* in_sizes, int n_in,
                              void* d_out, int out_size, void* d_ws, size_t ws_size,
                              hipStream_t stream) {
  const float* x = (const float*)d_in[0];
  const float* W0 = (const float*)d_in[1];
  const float* Wh = (const float*)d_in[2];
  const float* WL = (const float*)d_in[3];
  const float* bn_gamma = (const float*)d_in[4];
  const float* bn_beta = (const float*)d_in[5];
  const float* bn_mean = (const float*)d_in[6];
  const float* bn_var = (const float*)d_in[7];
  const float* bnL_gamma = (const float*)d_in[8];
  const float* bnL_beta = (const float*)d_in[9];
  const float* bnL_mean = (const float*)d_in[10];
  const float* bnL_var = (const float*)d_in[11];
  float* out = (float*)d_out;

  // workspace layout (needs ~275 MB)
  char* ws = (char*)d_ws;
  ushort* X0 = (ushort*)ws;                                   // 134217728 B
  ushort* X1 = (ushort*)(ws + 134217728);                     // 134217728 B
  char* wbase = ws + 268435456;
  ushort* W0b = (ushort*)(wbase);                             // 2 MiB
  ushort* Wh0b = (ushort*)(wbase + 2097152);                  // 2 MiB
  ushort* Wh1b = (ushort*)(wbase + 2 * 2097152);              // 2 MiB
  ushort* WLb = (ushort*)(wbase + 3 * 2097152);               // 32 KiB
  float* invstd3 = (float*)(wbase + 3 * 2097152 + 32768);     // 12 KiB
  float* invstdL = invstd3 + 3 * 1024;                        // 40 B

  hipLaunchKernelGGL(k_prep, dim3(1), dim3(1024), 0, stream,
                     bn_gamma, bn_var, bnL_gamma, bnL_var, WL, invstd3, invstdL, WLb);
  hipLaunchKernelGGL(k_binW, dim3(512), dim3(256), 0, stream, W0, W0b, 784);
  hipLaunchKernelGGL(k_binW, dim3(512), dim3(256), 0, stream, Wh, Wh0b, 1024);
  hipLaunchKernelGGL(k_binW, dim3(512), dim3(256), 0, stream, Wh + 1024 * 1024, Wh1b, 1024);
  hipLaunchKernelGGL(k_binX, dim3(32768), dim3(256), 0, stream, x, X0);

  dim3 g(8, 512);
  hipLaunchKernelGGL(gemm_bin, g, dim3(256), 0, stream, X0, W0b, X1,
                     bn_mean, bn_beta, invstd3);
  hipLaunchKernelGGL(gemm_bin, g, dim3(256), 0, stream, X1, Wh0b, X0,
                     bn_mean + 1024, bn_beta + 1024, invstd3 + 1024);
  hipLaunchKernelGGL(gemm_bin, g, dim3(256), 0, stream, X0, Wh1b, X1,
                     bn_mean + 2048, bn_beta + 2048, invstd3 + 2048);
  hipLaunchKernelGGL(gemm_fin, dim3(512), dim3(256), 0, stream, X1, WLb, out,
                     bnL_mean, bnL_beta, invstdL);
}

// Round 2
// 321.998 us; speedup vs baseline: 1.9906x; 1.9906x over previous
//
#include <hip/hip_runtime.h>
#include <hip/hip_bf16.h>
#include <stdint.h>

#define EPSF 1e-5f

typedef __attribute__((ext_vector_type(4))) int i32x4;
typedef __attribute__((ext_vector_type(16))) char c8x16;

__device__ __forceinline__ void gld_lds16(const void* g, void* l) {
  __builtin_amdgcn_global_load_lds((const __attribute__((address_space(1))) void*)g,
                                   (__attribute__((address_space(3))) void*)l, 16, 0, 0);
}

// ---------------- prep: binarize weights [1024 x Ksrc] f32 -> i8 [1024][1024], zero-pad ----------------
__global__ void k_binW(const float* __restrict__ src, char* __restrict__ dst, int Ksrc) {
  int t = blockIdx.x * 256 + threadIdx.x;  // 65536 threads, 16 i8 each
  int c = t & 63;                          // 16B chunk within 1024-col row
  int n = t >> 6;
  int kc = Ksrc >> 4;                      // 49 (784) or 64 (1024)
  c8x16 o;
  if (c < kc) {
    const float* p = src + (size_t)n * Ksrc + c * 16;
#pragma unroll
    for (int e = 0; e < 16; ++e) o[e] = (p[e] >= 0.0f) ? (char)1 : (char)-1;
  } else {
    o = (c8x16)0;
  }
  *(c8x16*)(dst + (size_t)t * 16) = o;
}

// ---------------- input binarize: x [65536 x 784] f32 -> X [65536 x 1024] i8 +-1, pad 0 ----------------
// sign(2x-1) == (x >= 0.5) exactly
__global__ void k_binX(const float* __restrict__ x, char* __restrict__ X) {
  size_t t = (size_t)blockIdx.x * 256 + threadIdx.x;  // 65536*64 threads
  int c = (int)(t & 63);
  size_t b = t >> 6;
  c8x16 o;
  if (c < 49) {  // 784 = 49*16
    const float* p = x + b * 784 + c * 16;
#pragma unroll
    for (int e = 0; e < 16; ++e) o[e] = (p[e] >= 0.5f) ? (char)1 : (char)-1;
  } else {
    o = (c8x16)0;
  }
  *(c8x16*)(X + b * 1024 + c * 16) = o;
}

// ---------------- small prep: inv_std (match numpy f32 rounding) + binarized WL [16][1024] i8 ----------------
__global__ void k_prep(const float* __restrict__ bn_gamma, const float* __restrict__ bn_var,
                       const float* __restrict__ bnL_gamma, const float* __restrict__ bnL_var,
                       const float* __restrict__ WL,
                       float* __restrict__ invstd3, float* __restrict__ invstdL,
                       char* __restrict__ WLb) {
  int j = threadIdx.x;  // 1024
#pragma unroll
  for (int i = 0; i < 3; ++i) {
    int idx = i * 1024 + j;
    invstd3[idx] = __fdiv_rn(bn_gamma[idx], __fsqrt_rn(__fadd_rn(bn_var[idx], EPSF)));
  }
  if (j < 10) invstdL[j] = __fdiv_rn(bnL_gamma[j], __fsqrt_rn(__fadd_rn(bnL_var[j], EPSF)));
#pragma unroll
  for (int r = 0; r < 16; ++r) {
    char v = 0;
    if (r < 10) v = (WL[r * 1024 + j] >= 0.0f) ? (char)1 : (char)-1;
    WLb[r * 1024 + j] = v;
  }
}

// ---------------- main fused GEMM: C_bin = binarize(BN(A @ Bt^T)), all i8 +-1 ----------------
// 128x128 tile, BK=64, 4 waves (2x2), 16 MFMA i32_16x16x64_i8 per K-step, global_load_lds w16.
// LDS chunk-swizzle: source chunk = c ^ (row&3) (global pre-swizzle), read slot = (l>>4)^(l&3).
// XCD decomposition: all 8 bn-blocks of one bm land on the same XCD (A panel fetched once).
__global__ __launch_bounds__(256, 2)
void gemm_bin(const char* __restrict__ A, const char* __restrict__ Bt,
              char* __restrict__ Cb,
              const float* __restrict__ mean, const float* __restrict__ beta,
              const float* __restrict__ invstd) {
  constexpr int K = 1024;
  __shared__ char sA[128 * 64];
  __shared__ char sB[128 * 64];
  const int tid = threadIdx.x;
  const int lane = tid & 63;
  const int wave = tid >> 6;
  const int d = blockIdx.x;          // 0..4095
  const int xcd = d & 7;
  const int idx = d >> 3;            // 0..511
  const int bm = xcd * 64 + (idx >> 3);
  const int bn = idx & 7;
  const int wm = wave >> 1, wn = wave & 1;

  // staging: thread tid -> row sr, source 16B-chunk swizzled by row&3; LDS write linear (tid*16)
  const int sr = tid >> 2;
  const int csrc = ((tid & 3) ^ (sr & 3)) << 4;
  const char* gA = A + (size_t)(bm * 128 + sr) * K + csrc;
  const char* gB = Bt + (size_t)(bn * 128 + sr) * K + csrc;
  char* lA = sA + (tid & ~63) * 16;
  char* lB = sB + (tid & ~63) * 16;

  // fragment reads: lane l -> row (l&15), k-chunk q=(l>>4); stored at slot q^(row&3)
  const int slot = ((lane >> 4) ^ (lane & 3)) << 4;
  const char* rA = sA + (wm * 64 + (lane & 15)) * 64 + slot;
  const char* rB = sB + (wn * 64 + (lane & 15)) * 64 + slot;

  i32x4 acc[4][4];
#pragma unroll
  for (int m = 0; m < 4; ++m)
#pragma unroll
    for (int n = 0; n < 4; ++n) acc[m][n] = (i32x4)0;

  for (int k0 = 0; k0 < K; k0 += 64) {
    gld_lds16(gA, lA);
    gld_lds16(gA + (size_t)64 * K, lA + 4096);
    gld_lds16(gB, lB);
    gld_lds16(gB + (size_t)64 * K, lB + 4096);
    gA += 64;
    gB += 64;
    __syncthreads();
    i32x4 af[4], bf[4];
#pragma unroll
    for (int m = 0; m < 4; ++m) af[m] = *(const i32x4*)(rA + m * 16 * 64);
#pragma unroll
    for (int n = 0; n < 4; ++n) bf[n] = *(const i32x4*)(rB + n * 16 * 64);
#pragma unroll
    for (int m = 0; m < 4; ++m)
#pragma unroll
      for (int n = 0; n < 4; ++n)
        acc[m][n] = __builtin_amdgcn_mfma_i32_16x16x64_i8(af[m], bf[n], acc[m][n], 0, 0, 0);
    __syncthreads();
  }

  // epilogue: exact int -> f32, BN with np-f32 rounding (no FMA), binarize to i8
  // C/D map: col = lane&15, row = (lane>>4)*4 + reg
  const int r0 = bm * 128 + wm * 64 + ((lane >> 4) << 2);
  const int c0 = bn * 128 + wn * 64 + (lane & 15);
#pragma unroll
  for (int n = 0; n < 4; ++n) {
    const int col = c0 + n * 16;
    const float mu = mean[col], bt = beta[col], is = invstd[col];
#pragma unroll
    for (int m = 0; m < 4; ++m) {
#pragma unroll
      for (int j = 0; j < 4; ++j) {
        const int row = r0 + m * 16 + j;
        float y = __fadd_rn(__fmul_rn(__fsub_rn((float)acc[m][n][j], mu), is), bt);
        Cb[(size_t)row * 1024 + col] = (y >= 0.0f) ? (char)1 : (char)-1;
      }
    }
  }
}

// ---------------- final layer: out[65536][10] = BN(A @ WLb^T), fp32 out, i8 inputs ----------------
__global__ __launch_bounds__(256, 2)
void gemm_fin(const char* __restrict__ A, const char* __restrict__ BtL,
              float* __restrict__ out,
              const float* __restrict__ meanL, const float* __restrict__ betaL,
              const float* __restrict__ invstdL) {
  constexpr int K = 1024;
  __shared__ char sA[128 * 64];
  __shared__ char sB[16 * 64];
  const int tid = threadIdx.x;
  const int lane = tid & 63;
  const int wave = tid >> 6;
  const int bm = blockIdx.x;

  const int sr = tid >> 2;
  const int csrc = ((tid & 3) ^ (sr & 3)) << 4;
  const char* gA = A + (size_t)(bm * 128 + sr) * K + csrc;
  const char* gB = BtL + (size_t)sr * K + csrc;  // only wave 0 (tid<64 -> rows 0..15)
  char* lA = sA + (tid & ~63) * 16;
  char* lB = sB;

  const int slot = ((lane >> 4) ^ (lane & 3)) << 4;
  const char* rA = sA + (wave * 32 + (lane & 15)) * 64 + slot;
  const char* rB = sB + (lane & 15) * 64 + slot;

  i32x4 acc0 = (i32x4)0, acc1 = (i32x4)0;

  for (int k0 = 0; k0 < K; k0 += 64) {
    gld_lds16(gA, lA);
    gld_lds16(gA + (size_t)64 * K, lA + 4096);
    if (tid < 64) gld_lds16(gB, lB);
    gA += 64;
    gB += 64;
    __syncthreads();
    i32x4 af0 = *(const i32x4*)(rA);
    i32x4 af1 = *(const i32x4*)(rA + 16 * 64);
    i32x4 b0 = *(const i32x4*)(rB);
    acc0 = __builtin_amdgcn_mfma_i32_16x16x64_i8(af0, b0, acc0, 0, 0, 0);
    acc1 = __builtin_amdgcn_mfma_i32_16x16x64_i8(af1, b0, acc1, 0, 0, 0);
    __syncthreads();
  }

  const int col = lane & 15;
  if (col < 10) {
    const float mu = meanL[col], bt = betaL[col], is = invstdL[col];
    const int r0 = bm * 128 + wave * 32 + ((lane >> 4) << 2);
#pragma unroll
    for (int m = 0; m < 2; ++m) {
      const i32x4 a = (m == 0) ? acc0 : acc1;
#pragma unroll
      for (int j = 0; j < 4; ++j) {
        const int row = r0 + m * 16 + j;
        out[(size_t)row * 10 + col] = __fadd_rn(__fmul_rn(__fsub_rn((float)a[j], mu), is), bt);
      }
    }
  }
}

extern "C" void kernel_launch(void* const* d_in, const int* in_sizes, int n_in,
                              void* d_out, int out_size, void* d_ws, size_t ws_size,
                              hipStream_t stream) {
  const float* x = (const float*)d_in[0];
  const float* W0 = (const float*)d_in[1];
  const float* Wh = (const float*)d_in[2];
  const float* WL = (const float*)d_in[3];
  const float* bn_gamma = (const float*)d_in[4];
  const float* bn_beta = (const float*)d_in[5];
  const float* bn_mean = (const float*)d_in[6];
  const float* bn_var = (const float*)d_in[7];
  const float* bnL_gamma = (const float*)d_in[8];
  const float* bnL_beta = (const float*)d_in[9];
  const float* bnL_mean = (const float*)d_in[10];
  const float* bnL_var = (const float*)d_in[11];
  float* out = (float*)d_out;

  // workspace layout (~140 MB)
  char* ws = (char*)d_ws;
  char* X0 = ws;                                   // 67108864 B
  char* X1 = ws + 67108864;                        // 67108864 B
  char* wbase = ws + 134217728;
  char* W0b = wbase;                               // 1 MiB
  char* Wh0b = wbase + 1048576;                    // 1 MiB
  char* Wh1b = wbase + 2 * 1048576;                // 1 MiB
  char* WLb = wbase + 3 * 1048576;                 // 16 KiB
  float* invstd3 = (float*)(wbase + 3 * 1048576 + 16384);  // 12 KiB
  float* invstdL = invstd3 + 3 * 1024;

  hipLaunchKernelGGL(k_prep, dim3(1), dim3(1024), 0, stream,
                     bn_gamma, bn_var, bnL_gamma, bnL_var, WL, invstd3, invstdL, WLb);
  hipLaunchKernelGGL(k_binW, dim3(256), dim3(256), 0, stream, W0, W0b, 784);
  hipLaunchKernelGGL(k_binW, dim3(256), dim3(256), 0, stream, Wh, Wh0b, 1024);
  hipLaunchKernelGGL(k_binW, dim3(256), dim3(256), 0, stream, Wh + 1024 * 1024, Wh1b, 1024);
  hipLaunchKernelGGL(k_binX, dim3(16384), dim3(256), 0, stream, x, X0);

  hipLaunchKernelGGL(gemm_bin, dim3(4096), dim3(256), 0, stream, X0, W0b, X1,
                     bn_mean, bn_beta, invstd3);
  hipLaunchKernelGGL(gemm_bin, dim3(4096), dim3(256), 0, stream, X1, Wh0b, X0,
                     bn_mean + 1024, bn_beta + 1024, invstd3 + 1024);
  hipLaunchKernelGGL(gemm_bin, dim3(4096), dim3(256), 0, stream, X0, Wh1b, X1,
                     bn_mean + 2048, bn_beta + 2048, invstd3 + 2048);
  hipLaunchKernelGGL(gemm_fin, dim3(512), dim3(256), 0, stream, X1, WLb, out,
                     bnL_mean, bnL_beta, invstdL);
}